// Round 13
// baseline (211.895 us; speedup 1.0000x reference)
//
#include <hip/hip_runtime.h>
#include <hip/hip_bf16.h>

// EdgeConv: N=16384 points, C=64, D=64, K=16 neighbors. All I/O fp32.
// R13: node-count attack (6 -> 4 graph nodes; ~10-15us per boundary measured
// across R3/R6/R10 residuals):
//   memset(counts) -> count_prep (count | prep | W2t build)
//     -> scan_scatter (single block: scan + same-block scatter)
//     -> knn_edge (selection per wave + REGISTER edge epilogue: h frag built
//        in-register from v_i/u_j, 8 MFMAs vs staged bf16 W2t, max+b2)
// Edge kernel, knn_out buffer, h-LDS all deleted. Selection numerics
// byte-identical to R12 (ref-formula distance, monotone u64 keys, bitonic
// warm start, append-and-flush, tau+1e-4 shell termination).

#define NPTS 16384
#define CH 64

#define GLO  (-4.5f)
#define GH   0.28125f          // 9/32
#define INVH 3.5555555556f     // 32/9
#define GDIM 32
#define GCELLS (GDIM * GDIM * GDIM)

typedef __attribute__((ext_vector_type(8))) short short8;
typedef __attribute__((ext_vector_type(4))) float floatx4;

__device__ __forceinline__ unsigned short f2bf(float f) {
    unsigned u = __float_as_uint(f);
    u += 0x7FFFu + ((u >> 16) & 1u);   // RNE
    return (unsigned short)(u >> 16);
}
__device__ __forceinline__ float bf2f(unsigned short u) {
    return __uint_as_float(((unsigned)u) << 16);
}
// wave64 inclusive scan via DPP (validated R11/R12)
__device__ __forceinline__ unsigned wave_iscan(unsigned x) {
    x += (unsigned)__builtin_amdgcn_update_dpp(0, (int)x, 0x111, 0xF, 0xF, true);
    x += (unsigned)__builtin_amdgcn_update_dpp(0, (int)x, 0x112, 0xF, 0xF, true);
    x += (unsigned)__builtin_amdgcn_update_dpp(0, (int)x, 0x114, 0xF, 0xF, true);
    x += (unsigned)__builtin_amdgcn_update_dpp(0, (int)x, 0x118, 0xF, 0xF, true);
    x += (unsigned)__builtin_amdgcn_update_dpp(0, (int)x, 0x142, 0xA, 0xF, true);
    x += (unsigned)__builtin_amdgcn_update_dpp(0, (int)x, 0x143, 0xC, 0xF, true);
    return x;
}
__device__ __forceinline__ int cell_of(float x, float y, float z) {
    int cx = (int)floorf((x - GLO) * INVH);
    int cy = (int)floorf((y - GLO) * INVH);
    int cz = (int)floorf((z - GLO) * INVH);
    cx = min(max(cx, 0), GDIM - 1);
    cy = min(max(cy, 0), GDIM - 1);
    cz = min(max(cz, 0), GDIM - 1);
    return (cz * GDIM + cy) * GDIM + cx;
}

// ---------------------------------------------------------------------------
// count_prep: blocks 0..63 count; 64..319 prep GEMM; 320 builds bf16 W2t.
//   prep: v_p = x_p@(W1a-W1b)+b1 -> vout(==d_out) ; u_p = x_p@W1b -> ubuf bf16
//   W2t[n*64+k] = bf16(W2[k*64+n])
// ---------------------------------------------------------------------------
__global__ __launch_bounds__(256) void count_prep_kernel(const float* __restrict__ pos,
                                                         int* __restrict__ counts,
                                                         const float* __restrict__ x,
                                                         const float* __restrict__ W1,
                                                         const float* __restrict__ b1,
                                                         const float* __restrict__ W2,
                                                         float* __restrict__ vout,
                                                         unsigned short* __restrict__ ubuf,
                                                         unsigned short* __restrict__ W2t) {
    __shared__ unsigned short Wct[128 * 72];
    __shared__ unsigned short Abuf[64 * 72];
    __shared__ float Wraw[128 * 64];

    const int t = threadIdx.x;
    if (blockIdx.x < 64) {
        const int i = blockIdx.x * 256 + t;
        atomicAdd(&counts[cell_of(pos[i * 3], pos[i * 3 + 1], pos[i * 3 + 2])], 1);
        return;
    }
    if (blockIdx.x == 320) {   // W2^T -> bf16 (4096 elems)
        for (int i = t; i < 4096; i += 256) {
            const int n = i >> 6, k = i & 63;
            W2t[n * 64 + k] = f2bf(W2[k * 64 + n]);
        }
        return;
    }
    const int bid  = blockIdx.x - 64;
    const int lane = t & 63;
    const int w    = t >> 6;

    {
        const float4* W1v = (const float4*)W1;
        float4* Wr4 = (float4*)Wraw;
#pragma unroll
        for (int i = 0; i < 8; ++i) Wr4[i * 256 + t] = W1v[i * 256 + t];
    }
    __syncthreads();
    {
        const int n = t & 127;
        const int ks = (t >> 7) * 32;
#pragma unroll
        for (int i = 0; i < 32; ++i) {
            const int k = ks + i;
            float val;
            if (n < 64) val = Wraw[k * 64 + n] - Wraw[(64 + k) * 64 + n];
            else        val = Wraw[(64 + k) * 64 + (n - 64)];
            Wct[n * 72 + k] = f2bf(val);
        }
    }
    {
        const int col = t & 63;
#pragma unroll
        for (int i = 0; i < 16; ++i) {
            const int r2 = (t >> 6) + 4 * i;
            const int gp = bid * 64 + r2;
            Abuf[r2 * 72 + col] = f2bf(x[(size_t)gp * CH + col]);
        }
    }
    __syncthreads();

    const int m16 = lane & 15;
    const int q   = lane >> 4;

    floatx4 acc[8];
#pragma unroll
    for (int nt = 0; nt < 8; ++nt) acc[nt] = (floatx4){0.f, 0.f, 0.f, 0.f};

#pragma unroll
    for (int kk = 0; kk < 64; kk += 32) {
        const short8 a = *(const short8*)(Abuf + (w * 16 + m16) * 72 + kk + q * 8);
#pragma unroll
        for (int nt = 0; nt < 8; ++nt) {
            const short8 b = *(const short8*)(Wct + (nt * 16 + m16) * 72 + kk + q * 8);
            acc[nt] = __builtin_amdgcn_mfma_f32_16x16x32_bf16(a, b, acc[nt], 0, 0, 0);
        }
    }

#pragma unroll
    for (int nt = 0; nt < 8; ++nt) {
        const int n = nt * 16 + m16;
#pragma unroll
        for (int r = 0; r < 4; ++r) {
            const int gp = bid * 64 + w * 16 + q * 4 + r;
            if (n < 64) vout[(size_t)gp * CH + n] = acc[nt][r] + b1[n];
            else        ubuf[(size_t)gp * CH + (n - 64)] = f2bf(acc[nt][r]);
        }
    }
}

// ---------------------------------------------------------------------------
// scan_scatter: ONE block of 1024. Scan counts -> starts (+sentinel) + global
// cursor; __syncthreads drains stores (visible in L2); same block scatters
// all points via global-cursor atomics. starts[GCELLS] = NPTS sentinel.
// ---------------------------------------------------------------------------
__global__ __launch_bounds__(1024) void scan_scatter_kernel(const float* __restrict__ pos,
                                                            const int* __restrict__ counts,
                                                            int* __restrict__ starts,
                                                            int* __restrict__ cursor,
                                                            float4* __restrict__ spos,
                                                            unsigned short* __restrict__ sidx) {
    __shared__ int wsum[16];
    const int t    = threadIdx.x;
    const int lane = t & 63;
    const int wv   = t >> 6;

    int4 v[8];
    const int4* c4 = (const int4*)counts + t * 8;
#pragma unroll
    for (int i = 0; i < 8; ++i) v[i] = c4[i];
    int sum = 0;
#pragma unroll
    for (int i = 0; i < 8; ++i) sum += v[i].x + v[i].y + v[i].z + v[i].w;

    const unsigned incl = wave_iscan((unsigned)sum);
    if (lane == 63) wsum[wv] = (int)incl;
    __syncthreads();
    int base = (int)incl - sum;
    for (int k = 0; k < wv; ++k) base += wsum[k];

    int pre = base;
    int4* s4 = (int4*)starts + t * 8;
    int4* u4 = (int4*)cursor + t * 8;
#pragma unroll
    for (int i = 0; i < 8; ++i) {
        int4 o;
        o.x = pre; pre += v[i].x;
        o.y = pre; pre += v[i].y;
        o.z = pre; pre += v[i].z;
        o.w = pre; pre += v[i].w;
        s4[i] = o;
        u4[i] = o;
    }
    if (t == 1023) starts[GCELLS] = pre;   // == NPTS
    __syncthreads();   // vmcnt drained -> cursor stores visible to L2 atomics

    for (int i = t; i < NPTS; i += 1024) {
        const float a = pos[i * 3], b = pos[i * 3 + 1], c = pos[i * 3 + 2];
        const int dst = atomicAdd(&cursor[cell_of(a, b, c)], 1);
        spos[dst] = make_float4(a, b, c, a * a + b * b + c * c);
        sidx[dst] = (unsigned short)i;
    }
}

// ---------------------------------------------------------------------------
// knn_edge: block = 128 thr (2 waves), 1 SORTED query per wave.
// Selection identical to R12 (run-compaction + append-and-flush).
// Then register edge epilogue: h=f2bf(relu(v_i+u_j)) built in-register,
// 8 MFMAs vs W2t, max over 16 rows, +b2, store out[qrow].
// ---------------------------------------------------------------------------
#define SENT 0xFF800000FFFFFFFFULL   // key(+inf) | idx-all-ones
#define NB 4

__global__ __launch_bounds__(128) void knn_edge_kernel(const float4* __restrict__ spos,
                                                       const unsigned short* __restrict__ sidx,
                                                       const int* __restrict__ starts,
                                                       const unsigned short* __restrict__ ubuf,
                                                       const unsigned short* __restrict__ W2t,
                                                       const float* __restrict__ b2,
                                                       float* __restrict__ out) {
    __shared__ int lds_ex[128];
    __shared__ int lds_st[128];
    __shared__ unsigned long long bufs[128];
    const int lane  = threadIdx.x & 63;
    const int w     = threadIdx.x >> 6;
    int* ex = lds_ex + w * 64;
    int* st_ = lds_st + w * 64;
    unsigned long long* buf = bufs + w * 64;
    const int sq = blockIdx.x * 2 + w;

    const float4 qv = spos[sq];
    const float qx = qv.x, qy = qv.y, qz = qv.z, sqi = qv.w;
    const int qrow = (int)sidx[sq];
    const int cix = min(max((int)floorf((qx - GLO) * INVH), 0), GDIM - 1);
    const int ciy = min(max((int)floorf((qy - GLO) * INVH), 0), GDIM - 1);
    const int ciz = min(max((int)floorf((qz - GLO) * INVH), 0), GDIM - 1);

    unsigned long long list = SENT;
    float tau = __uint_as_float(0x7F800000u);
    bool first = true;
    int nbuf = 0;

    auto do_flush = [&]() {
        unsigned long long ck = (lane < nbuf) ? buf[lane] : SENT;
#pragma unroll
        for (int k = 2; k <= 64; k <<= 1) {
#pragma unroll
            for (int jj = k >> 1; jj >= 1; jj >>= 1) {
                const unsigned long long o = __shfl_xor(ck, jj);
                const bool takeMin = (((lane & k) == 0) == ((lane & jj) == 0));
                const unsigned long long mn = (ck < o) ? ck : o;
                const unsigned long long mx = (ck < o) ? o : ck;
                ck = takeMin ? mn : mx;
            }
        }
        const unsigned long long cv = __shfl(ck, 31 - lane);
        unsigned long long m = SENT;
        if (lane < 16) m = list;
        else if (lane < 32) m = cv;
#pragma unroll
        for (int jj = 16; jj >= 1; jj >>= 1) {
            const unsigned long long o = __shfl_xor(m, jj);
            const unsigned long long mn = (m < o) ? m : o;
            const unsigned long long mx = (m < o) ? o : m;
            m = ((lane & jj) == 0) ? mn : mx;
        }
        list = m;
        const unsigned thi = (unsigned)__builtin_amdgcn_readlane(
            (int)(unsigned)(list >> 32), 15);
        const unsigned fb = (thi >= 0x80000000u) ? (thi & 0x7FFFFFFFu) : ~thi;
        tau = __uint_as_float(fb);
        nbuf = 0;
    };

    int pax = 1, pbx = 0, pay = 1, pby = 0, paz = 1, pbz = 0;

    for (int s = 1; s < GDIM + 1; ++s) {
        const int ax = max(cix - s, 0), bx = min(cix + s, GDIM - 1);
        const int ay = max(ciy - s, 0), by = min(ciy + s, GDIM - 1);
        const int az = max(ciz - s, 0), bz = min(ciz + s, GDIM - 1);
        const int dy = by - ay + 1, dz = bz - az + 1;
        const int npair = dy * dz;
        const float invdy = 1.0f / (float)dy;

        for (int pb = 0; pb < npair; pb += 64) {
            const int pair = pb + lane;
            int stA = 0, lenA = 0, stB = 0, lenB = 0;
            if (pair < npair) {
                const int czo = (int)(((float)pair + 0.5f) * invdy);
                const int cyo = pair - czo * dy;
                const int cy = ay + cyo, cz = az + czo;
                const int rowb = (cz * GDIM + cy) * GDIM;
                const bool inner = cy >= pay && cy <= pby && cz >= paz && cz <= pbz;
                const int bA = inner ? (pax - 1) : bx;
                if (bA >= ax) {
                    stA  = starts[rowb + ax];
                    lenA = starts[rowb + bA + 1] - stA;
                }
                if (inner) {
                    const int aB = pbx + 1;
                    if (bx >= aB) {
                        stB  = starts[rowb + aB];
                        lenB = starts[rowb + bx + 1] - stB;
                    }
                }
            }
#pragma unroll
            for (int setsel = 0; setsel < 2; ++setsel) {
                const int st  = setsel ? stB  : stA;
                const int len = setsel ? lenB : lenA;
                if (__ballot(len > 0) == 0ULL) continue;
                const unsigned pfx = wave_iscan((unsigned)len);
                const int T = __builtin_amdgcn_readlane((int)pfx, 63);
                ex[lane] = (int)pfx - len;
                st_[lane] = st;

                for (int b0 = 0; b0 < T; b0 += 64 * NB) {
                    float4 pts[NB];
                    int    jor[NB];
                    bool   act[NB];
                    bool   live[NB];
#pragma unroll
                    for (int nb = 0; nb < NB; ++nb) {
                        const int bb = b0 + nb * 64;
                        live[nb] = bb < T;
                        act[nb] = false;
                        if (live[nb]) {
                            const int p = bb + lane;
                            int j = 0;
#pragma unroll
                            for (int stp = 32; stp >= 1; stp >>= 1) {
                                const int m = j + stp;
                                if (ex[m] <= p) j = m;
                            }
                            int idx = st_[j] + (p - ex[j]);
                            idx = min(idx, NPTS - 1);
                            act[nb] = p < T;
                            pts[nb] = spos[idx];
                            jor[nb] = (int)sidx[idx];
                        }
                    }
#pragma unroll
                    for (int nb = 0; nb < NB; ++nb) {
                        if (!live[nb]) continue;
                        const float dot = fmaf(qx, pts[nb].x,
                                               fmaf(qy, pts[nb].y, qz * pts[nb].z));
                        const float d = fmaf(-2.0f, dot, sqi + pts[nb].w);

                        if (first) {
                            first = false;
                            unsigned kd = __float_as_uint(d);
                            kd = ((int)kd < 0) ? ~kd : (kd | 0x80000000u);
                            unsigned long long key =
                                (((unsigned long long)kd) << 32) | (unsigned)jor[nb];
                            if (!(act[nb] && jor[nb] != qrow)) key = SENT;
#pragma unroll
                            for (int k = 2; k <= 64; k <<= 1) {
#pragma unroll
                                for (int jj = k >> 1; jj >= 1; jj >>= 1) {
                                    const unsigned long long o = __shfl_xor(key, jj);
                                    const bool takeMin =
                                        (((lane & k) == 0) == ((lane & jj) == 0));
                                    const unsigned long long mn = (key < o) ? key : o;
                                    const unsigned long long mx = (key < o) ? o : key;
                                    key = takeMin ? mn : mx;
                                }
                            }
                            list = key;
                            const unsigned thi = (unsigned)__builtin_amdgcn_readlane(
                                (int)(unsigned)(list >> 32), 15);
                            const unsigned fb =
                                (thi >= 0x80000000u) ? (thi & 0x7FFFFFFFu) : ~thi;
                            tau = __uint_as_float(fb);
                            continue;
                        }

                        const bool cand = act[nb] && (jor[nb] != qrow) && (d <= tau);
                        const unsigned long long mask = __ballot(cand);
                        if (mask) {
                            const int cnt = __popcll(mask);
                            if (nbuf + cnt > 64) do_flush();
                            if (cand) {
                                unsigned kd = __float_as_uint(d);
                                kd = ((int)kd < 0) ? ~kd : (kd | 0x80000000u);
                                const unsigned long long key =
                                    (((unsigned long long)kd) << 32) | (unsigned)jor[nb];
                                const int rank =
                                    __popcll(mask & ((1ULL << lane) - 1ULL));
                                buf[nbuf + rank] = key;
                            }
                            nbuf += cnt;
                        }
                    }
                }
            }
        }

        if (nbuf) do_flush();

        const float BIG = 1e30f;
        float dout = BIG;
        if (ax > 0)        dout = fminf(dout, qx - (GLO + ax * GH));
        if (bx < GDIM - 1) dout = fminf(dout, (GLO + (bx + 1) * GH) - qx);
        if (ay > 0)        dout = fminf(dout, qy - (GLO + ay * GH));
        if (by < GDIM - 1) dout = fminf(dout, (GLO + (by + 1) * GH) - qy);
        if (az > 0)        dout = fminf(dout, qz - (GLO + az * GH));
        if (bz < GDIM - 1) dout = fminf(dout, (GLO + (bz + 1) * GH) - qz);
        if (dout * dout > tau + 1e-4f) break;
        if (ax == 0 && bx == GDIM - 1 && ay == 0 && by == GDIM - 1 &&
            az == 0 && bz == GDIM - 1) break;
        pax = ax; pbx = bx; pay = ay; pby = by; paz = az; pbz = bz;
    }

    // ======== register edge epilogue (replaces edge_kernel) ========
    {
        const int m16 = lane & 15;
        const int q   = lane >> 4;
        const int j   = (int)(unsigned)(__shfl(list, m16) & 0xFFFFULL);

        short8 hfrag[2];
#pragma unroll
        for (int kk2 = 0; kk2 < 2; ++kk2) {
            const int kk = kk2 * 32;
            const float*  vp = out  + (size_t)qrow * CH + kk + q * 8;
            const ushort4 u0 = *(const ushort4*)(ubuf + (size_t)j * CH + kk + q * 8);
            const ushort4 u1 = *(const ushort4*)(ubuf + (size_t)j * CH + kk + q * 8 + 4);
            const float4 v0 = *(const float4*)(vp);
            const float4 v1 = *(const float4*)(vp + 4);
            short8 h;
            h[0] = (short)f2bf(fmaxf(v0.x + bf2f(u0.x), 0.f));
            h[1] = (short)f2bf(fmaxf(v0.y + bf2f(u0.y), 0.f));
            h[2] = (short)f2bf(fmaxf(v0.z + bf2f(u0.z), 0.f));
            h[3] = (short)f2bf(fmaxf(v0.w + bf2f(u0.w), 0.f));
            h[4] = (short)f2bf(fmaxf(v1.x + bf2f(u1.x), 0.f));
            h[5] = (short)f2bf(fmaxf(v1.y + bf2f(u1.y), 0.f));
            h[6] = (short)f2bf(fmaxf(v1.z + bf2f(u1.z), 0.f));
            h[7] = (short)f2bf(fmaxf(v1.w + bf2f(u1.w), 0.f));
            hfrag[kk2] = h;
        }

        floatx4 acc[4];
#pragma unroll
        for (int nt = 0; nt < 4; ++nt) acc[nt] = (floatx4){0.f, 0.f, 0.f, 0.f};
#pragma unroll
        for (int kk2 = 0; kk2 < 2; ++kk2) {
#pragma unroll
            for (int nt = 0; nt < 4; ++nt) {
                const short8 b =
                    *(const short8*)(W2t + (nt * 16 + m16) * 64 + kk2 * 32 + q * 8);
                acc[nt] = __builtin_amdgcn_mfma_f32_16x16x32_bf16(hfrag[kk2], b,
                                                                  acc[nt], 0, 0, 0);
            }
        }
#pragma unroll
        for (int nt = 0; nt < 4; ++nt) {
            float m0 = fmaxf(fmaxf(acc[nt][0], acc[nt][1]),
                             fmaxf(acc[nt][2], acc[nt][3]));
            m0 = fmaxf(m0, __shfl_xor(m0, 16));
            m0 = fmaxf(m0, __shfl_xor(m0, 32));
            if (lane < 16)
                out[(size_t)qrow * CH + nt * 16 + lane] = m0 + b2[nt * 16 + lane];
        }
    }
}

extern "C" void kernel_launch(void* const* d_in, const int* in_sizes, int n_in,
                              void* d_out, int out_size, void* d_ws, size_t ws_size,
                              hipStream_t stream) {
    const float* x   = (const float*)d_in[0];
    const float* pos = (const float*)d_in[1];
    const float* W1  = (const float*)d_in[2];
    const float* b1  = (const float*)d_in[3];
    const float* W2  = (const float*)d_in[4];
    const float* b2  = (const float*)d_in[5];
    float* out = (float*)d_out;

    char* ws = (char*)d_ws;
    unsigned short* ubuf = (unsigned short*)(ws + 524288);         // 2 MB
    int*    counts = (int*)(ws + 2621440);                         // 128 KB
    int*    starts = (int*)(ws + 2752512);                         // 128 KB + sentinel
    int*    cursor = (int*)(ws + 2883600);                         // 128 KB
    float4* spos   = (float4*)(ws + 3014672);                      // 256 KB
    unsigned short* sidx = (unsigned short*)(ws + 3276816);        // 32 KB
    unsigned short* W2t  = (unsigned short*)(ws + 3309584);        // 8 KB

    hipMemsetAsync(counts, 0, GCELLS * sizeof(int), stream);
    count_prep_kernel<<<321, 256, 0, stream>>>(pos, counts, x, W1, b1, W2,
                                               out, ubuf, W2t);
    scan_scatter_kernel<<<1, 1024, 0, stream>>>(pos, counts, starts, cursor,
                                                spos, sidx);
    knn_edge_kernel<<<NPTS / 2, 128, 0, stream>>>(spos, sidx, starts, ubuf,
                                                  W2t, b2, out);
}

// Round 14
// 186.076 us; speedup vs baseline: 1.1388x; 1.1388x over previous
//
#include <hip/hip_runtime.h>
#include <hip/hip_bf16.h>

// EdgeConv: N=16384 points, C=64, D=64, K=16 neighbors. All I/O fp32.
// Pipeline (R10 skeleton -- best known, 144.8us; R13's fusions reverted:
// single-block scatter serialized atomics on 1 CU, epilogue fusion added
// per-wave tail latency):
//   memset(counts) -> [count | prep fused] -> scan -> scatter -> knn -> edge
// R14 knn: 16-LANE SUBGROUPS -- 4 queries per wave (cells hold ~0.5..23 pts,
// so 64-wide screens ran mostly-idle lanes). DPP row ops are natively
// 16-lane-local (scan shr1/2/4/8, insert shift); bitonic-16 via shfl_xor;
// ballots sliced per group; tau/T via __shfl(x, g*16+15). Groups' divergent
// loops overlap under exec mask -> per-wave serial ~ max not sum of 4.
// Numerics identical to R10.

#define NPTS 16384
#define CH 64

#define GLO  (-4.5f)
#define GH   0.28125f          // 9/32
#define INVH 3.5555555556f     // 32/9
#define GDIM 32
#define GCELLS (GDIM * GDIM * GDIM)

typedef __attribute__((ext_vector_type(8))) short short8;
typedef __attribute__((ext_vector_type(4))) float floatx4;

__device__ __forceinline__ unsigned short f2bf(float f) {
    unsigned u = __float_as_uint(f);
    u += 0x7FFFu + ((u >> 16) & 1u);   // RNE
    return (unsigned short)(u >> 16);
}
__device__ __forceinline__ float bf2f(unsigned short u) {
    return __uint_as_float(((unsigned)u) << 16);
}
// inclusive prefix scan within each 16-lane row (DPP row_shr, 0-fill)
__device__ __forceinline__ unsigned row_iscan16(unsigned x) {
    x += (unsigned)__builtin_amdgcn_update_dpp(0, (int)x, 0x111, 0xF, 0xF, true);
    x += (unsigned)__builtin_amdgcn_update_dpp(0, (int)x, 0x112, 0xF, 0xF, true);
    x += (unsigned)__builtin_amdgcn_update_dpp(0, (int)x, 0x114, 0xF, 0xF, true);
    x += (unsigned)__builtin_amdgcn_update_dpp(0, (int)x, 0x118, 0xF, 0xF, true);
    return x;
}
// 64-bit shift-by-1 within each 16-lane row (row starts get 0)
__device__ __forceinline__ unsigned long long dpp_shr1_u64(unsigned long long x) {
    int lo = (int)(unsigned)(x & 0xFFFFFFFFULL);
    int hi = (int)(unsigned)(x >> 32);
    lo = __builtin_amdgcn_update_dpp(0, lo, 0x111, 0xF, 0xF, false);
    hi = __builtin_amdgcn_update_dpp(0, hi, 0x111, 0xF, 0xF, false);
    return (((unsigned long long)(unsigned)hi) << 32) | (unsigned)lo;
}
__device__ __forceinline__ int cell_of(float x, float y, float z) {
    int cx = (int)floorf((x - GLO) * INVH);
    int cy = (int)floorf((y - GLO) * INVH);
    int cz = (int)floorf((z - GLO) * INVH);
    cx = min(max(cx, 0), GDIM - 1);
    cy = min(max(cy, 0), GDIM - 1);
    cz = min(max(cz, 0), GDIM - 1);
    return (cz * GDIM + cy) * GDIM + cx;
}

// ---------------------------------------------------------------------------
// Fused: blocks 0..63 = grid count (atomics); blocks 64..319 = prep GEMM
// ---------------------------------------------------------------------------
__global__ __launch_bounds__(256) void count_prep_kernel(const float* __restrict__ pos,
                                                         int* __restrict__ counts,
                                                         const float* __restrict__ x,
                                                         const float* __restrict__ W1,
                                                         const float* __restrict__ b1,
                                                         float* __restrict__ vout,
                                                         unsigned short* __restrict__ ubuf) {
    __shared__ unsigned short Wct[128 * 72];
    __shared__ unsigned short Abuf[64 * 72];
    __shared__ float Wraw[128 * 64];

    const int t = threadIdx.x;
    if (blockIdx.x < 64) {
        const int i = blockIdx.x * 256 + t;
        atomicAdd(&counts[cell_of(pos[i * 3], pos[i * 3 + 1], pos[i * 3 + 2])], 1);
        return;
    }
    const int bid  = blockIdx.x - 64;
    const int lane = t & 63;
    const int w    = t >> 6;

    {
        const float4* W1v = (const float4*)W1;
        float4* Wr4 = (float4*)Wraw;
#pragma unroll
        for (int i = 0; i < 8; ++i) Wr4[i * 256 + t] = W1v[i * 256 + t];
    }
    __syncthreads();
    {
        const int n = t & 127;
        const int ks = (t >> 7) * 32;
#pragma unroll
        for (int i = 0; i < 32; ++i) {
            const int k = ks + i;
            float val;
            if (n < 64) val = Wraw[k * 64 + n] - Wraw[(64 + k) * 64 + n];
            else        val = Wraw[(64 + k) * 64 + (n - 64)];
            Wct[n * 72 + k] = f2bf(val);
        }
    }
    {
        const int col = t & 63;
#pragma unroll
        for (int i = 0; i < 16; ++i) {
            const int r2 = (t >> 6) + 4 * i;
            const int gp = bid * 64 + r2;
            Abuf[r2 * 72 + col] = f2bf(x[(size_t)gp * CH + col]);
        }
    }
    __syncthreads();

    const int m16 = lane & 15;
    const int q   = lane >> 4;

    floatx4 acc[8];
#pragma unroll
    for (int nt = 0; nt < 8; ++nt) acc[nt] = (floatx4){0.f, 0.f, 0.f, 0.f};

#pragma unroll
    for (int kk = 0; kk < 64; kk += 32) {
        const short8 a = *(const short8*)(Abuf + (w * 16 + m16) * 72 + kk + q * 8);
#pragma unroll
        for (int nt = 0; nt < 8; ++nt) {
            const short8 b = *(const short8*)(Wct + (nt * 16 + m16) * 72 + kk + q * 8);
            acc[nt] = __builtin_amdgcn_mfma_f32_16x16x32_bf16(a, b, acc[nt], 0, 0, 0);
        }
    }

#pragma unroll
    for (int nt = 0; nt < 8; ++nt) {
        const int n = nt * 16 + m16;
#pragma unroll
        for (int r = 0; r < 4; ++r) {
            const int gp = bid * 64 + w * 16 + q * 4 + r;
            if (n < 64) vout[(size_t)gp * CH + n] = acc[nt][r] + b1[n];
            else        ubuf[(size_t)gp * CH + (n - 64)] = f2bf(acc[nt][r]);
        }
    }
}

// starts has GCELLS+1 entries; starts[GCELLS] = NPTS sentinel (run ends).
__global__ __launch_bounds__(1024) void scan_kernel(const int* __restrict__ counts,
                                                    int* __restrict__ starts,
                                                    int* __restrict__ cursor) {
    __shared__ int lds[1024];
    const int t = threadIdx.x;
    int4 v[8];
    const int4* c4 = (const int4*)counts + t * 8;
#pragma unroll
    for (int i = 0; i < 8; ++i) v[i] = c4[i];
    int sum = 0;
#pragma unroll
    for (int i = 0; i < 8; ++i) sum += v[i].x + v[i].y + v[i].z + v[i].w;
    lds[t] = sum;
    __syncthreads();
    for (int off = 1; off < 1024; off <<= 1) {
        int x = 0;
        if (t >= off) x = lds[t - off];
        __syncthreads();
        lds[t] += x;
        __syncthreads();
    }
    int pre = (t == 0) ? 0 : lds[t - 1];
    int4* s4 = (int4*)starts + t * 8;
    int4* u4 = (int4*)cursor + t * 8;
#pragma unroll
    for (int i = 0; i < 8; ++i) {
        int4 o;
        o.x = pre; pre += v[i].x;
        o.y = pre; pre += v[i].y;
        o.z = pre; pre += v[i].z;
        o.w = pre; pre += v[i].w;
        s4[i] = o;
        u4[i] = o;
    }
    if (t == 1023) starts[GCELLS] = pre;   // == NPTS
}

__global__ __launch_bounds__(256) void grid_scatter_kernel(const float* __restrict__ pos,
                                                           int* __restrict__ cursor,
                                                           float4* __restrict__ spos,
                                                           unsigned short* __restrict__ sidx) {
    const int i = blockIdx.x * 256 + threadIdx.x;
    const float a = pos[i * 3], b = pos[i * 3 + 1], c = pos[i * 3 + 2];
    const int dst = atomicAdd(&cursor[cell_of(a, b, c)], 1);
    spos[dst] = make_float4(a, b, c, a * a + b * b + c * c);  // same sq expr as query side
    sidx[dst] = (unsigned short)i;
}

// ---------------------------------------------------------------------------
// Grid KNN, 16-lane subgroups: 4 queries/wave, 16 queries/block (256 thr).
// Per group: run-compaction (16-wide), DPP row scan, bitonic-16 warm start,
// per-event distributed insert (dpp row shift). Numerics identical to R10.
// ---------------------------------------------------------------------------
#define SENT 0xFF800000FFFFFFFFULL   // key(+inf) | idx-all-ones

__global__ __launch_bounds__(256) void knn_grid_kernel(const float* __restrict__ pos,
                                                       const float4* __restrict__ spos,
                                                       const unsigned short* __restrict__ sidx,
                                                       const int* __restrict__ starts,
                                                       unsigned short* __restrict__ knn_out) {
    __shared__ int lds_ex[256];
    __shared__ int lds_st[256];
    const int t    = threadIdx.x;
    const int lane = t & 63;
    const int w    = t >> 6;
    const int g    = lane >> 4;      // subgroup 0..3
    const int l16  = lane & 15;
    const int gb   = g * 16;         // group lane base within wave
    int* exg = lds_ex + w * 64 + gb; // 16 ints per group
    int* stg = lds_st + w * 64 + gb;

    const int row = blockIdx.x * 16 + w * 4 + g;   // this group's query

    const float qx = pos[row * 3 + 0];
    const float qy = pos[row * 3 + 1];
    const float qz = pos[row * 3 + 2];
    const float sqi = qx * qx + qy * qy + qz * qz;
    const int cix = min(max((int)floorf((qx - GLO) * INVH), 0), GDIM - 1);
    const int ciy = min(max((int)floorf((qy - GLO) * INVH), 0), GDIM - 1);
    const int ciz = min(max((int)floorf((qz - GLO) * INVH), 0), GDIM - 1);

    unsigned long long list = SENT;
    float tau = __uint_as_float(0x7F800000u);   // +INF
    bool first = true;
    bool done = false;

    int pax = 1, pbx = 0, pay = 1, pby = 0, paz = 1, pbz = 0;  // empty prev cube

    for (int s = 1; s < GDIM + 1; ++s) {
        if (!done) {
            const int ax = max(cix - s, 0), bx = min(cix + s, GDIM - 1);
            const int ay = max(ciy - s, 0), by = min(ciy + s, GDIM - 1);
            const int az = max(ciz - s, 0), bz = min(ciz + s, GDIM - 1);
            const int dy = by - ay + 1, dz = bz - az + 1;
            const int npair = dy * dz;
            const float invdy = 1.0f / (float)dy;

            for (int pb = 0; pb < npair; pb += 16) {
                const int pair = pb + l16;
                int stA = 0, lenA = 0, stB = 0, lenB = 0;
                if (pair < npair) {
                    const int czo = (int)(((float)pair + 0.5f) * invdy);
                    const int cyo = pair - czo * dy;
                    const int cy = ay + cyo, cz = az + czo;
                    const int rowb = (cz * GDIM + cy) * GDIM;
                    const bool inner = cy >= pay && cy <= pby && cz >= paz && cz <= pbz;
                    const int bA = inner ? (pax - 1) : bx;
                    if (bA >= ax) {
                        stA  = starts[rowb + ax];
                        lenA = starts[rowb + bA + 1] - stA;
                    }
                    if (inner) {
                        const int aB = pbx + 1;
                        if (bx >= aB) {
                            stB  = starts[rowb + aB];
                            lenB = starts[rowb + bx + 1] - stB;
                        }
                    }
                }
#pragma unroll
                for (int setsel = 0; setsel < 2; ++setsel) {
                    const int st  = setsel ? stB  : stA;
                    const int len = setsel ? lenB : lenA;
                    const unsigned gm_len =
                        (unsigned)((__ballot(len > 0) >> gb) & 0xFFFFULL);
                    if (!gm_len) continue;
                    const unsigned pfx = row_iscan16((unsigned)len);
                    const int T = (int)(unsigned)__shfl(pfx, gb + 15);
                    exg[l16] = (int)pfx - len;
                    stg[l16] = st;

                    for (int b0 = 0; b0 < T; b0 += 16) {
                        const int p = b0 + l16;
                        int j = 0;
#pragma unroll
                        for (int stp = 8; stp >= 1; stp >>= 1) {
                            const int m = j + stp;
                            if (exg[m] <= p) j = m;
                        }
                        int idx = stg[j] + (p - exg[j]);
                        idx = min(idx, NPTS - 1);
                        const bool active = p < T;
                        const float4 pt = spos[idx];
                        const int jorig = (int)sidx[idx];
                        // reference-formula distance (identical to R10)
                        const float dot = fmaf(qx, pt.x, fmaf(qy, pt.y, qz * pt.z));
                        const float d   = fmaf(-2.0f, dot, sqi + pt.w);

                        if (first) {
                            first = false;
                            unsigned kd = __float_as_uint(d);
                            kd = ((int)kd < 0) ? ~kd : (kd | 0x80000000u);
                            unsigned long long key =
                                (((unsigned long long)kd) << 32) | (unsigned)jorig;
                            if (!(active && jorig != row)) key = SENT;
                            // bitonic-16 sort ascending within group
#pragma unroll
                            for (int k = 2; k <= 16; k <<= 1) {
#pragma unroll
                                for (int jj = k >> 1; jj >= 1; jj >>= 1) {
                                    const unsigned long long o = __shfl_xor(key, jj);
                                    const bool takeMin =
                                        (((l16 & k) == 0) == ((l16 & jj) == 0));
                                    const unsigned long long mn = (key < o) ? key : o;
                                    const unsigned long long mx = (key < o) ? o : key;
                                    key = takeMin ? mn : mx;
                                }
                            }
                            list = key;
                            const unsigned thi = (unsigned)(unsigned long long)
                                (__shfl(list, gb + 15) >> 32);
                            const unsigned fb =
                                (thi >= 0x80000000u) ? (thi & 0x7FFFFFFFu) : ~thi;
                            tau = __uint_as_float(fb);
                            continue;
                        }

                        const bool cand = active && (jorig != row) && (d <= tau);
                        unsigned gm =
                            (unsigned)((__ballot(cand) >> gb) & 0xFFFFULL);
                        if (gm) {
                            unsigned kd = __float_as_uint(d);
                            kd = ((int)kd < 0) ? ~kd : (kd | 0x80000000u);
                            do {
                                const int src = gb + (__ffs(gm) - 1);
                                gm &= gm - 1;
                                const unsigned slo = (unsigned)__shfl(jorig, src);
                                const unsigned shi = (unsigned)__shfl((int)kd, src);
                                const unsigned long long v =
                                    (((unsigned long long)shi) << 32) | slo;
                                const unsigned long long prev = dpp_shr1_u64(list);
                                const unsigned long long lr = list;
                                list = (lr < v) ? lr : ((prev < v) ? v : prev);
                            } while (gm);
                            const unsigned thi = (unsigned)(unsigned long long)
                                (__shfl(list, gb + 15) >> 32);
                            const unsigned fb =
                                (thi >= 0x80000000u) ? (thi & 0x7FFFFFFFu) : ~thi;
                            tau = __uint_as_float(fb);
                        }
                    }
                }
            }

            // termination (1e-4 margin, identical to R10)
            const float BIG = 1e30f;
            float dout = BIG;
            if (ax > 0)        dout = fminf(dout, qx - (GLO + ax * GH));
            if (bx < GDIM - 1) dout = fminf(dout, (GLO + (bx + 1) * GH) - qx);
            if (ay > 0)        dout = fminf(dout, qy - (GLO + ay * GH));
            if (by < GDIM - 1) dout = fminf(dout, (GLO + (by + 1) * GH) - qy);
            if (az > 0)        dout = fminf(dout, qz - (GLO + az * GH));
            if (bz < GDIM - 1) dout = fminf(dout, (GLO + (bz + 1) * GH) - qz);
            if (dout * dout > tau + 1e-4f) done = true;
            if (ax == 0 && bx == GDIM - 1 && ay == 0 && by == GDIM - 1 &&
                az == 0 && bz == GDIM - 1) done = true;
            if (!done) {
                pax = ax; pbx = bx; pay = ay; pby = by; paz = az; pbz = bz;
            }
        }
        if (__ballot(!done) == 0ULL) break;
    }

    knn_out[row * 16 + l16] = (unsigned short)(list & 0xFFFFULL);
}

// ---------------------------------------------------------------------------
// edge: block = 8 points (128 edge rows). h = relu(v_i + u_j) staged bf16 in
// LDS; GEMM2 (128x64)@(64x64) via MFMA; max over each point's 16 rows; +b2.
// ---------------------------------------------------------------------------
__global__ __launch_bounds__(256) void edge_kernel(const unsigned short* __restrict__ ubuf,
                                                   const float* __restrict__ W2,
                                                   const float* __restrict__ b2,
                                                   const unsigned short* __restrict__ knn,
                                                   float* __restrict__ out) {
    __shared__ unsigned short h[128 * 72];
    __shared__ unsigned short W2t[64 * 72];

    const int t    = threadIdx.x;
    const int lane = t & 63;
    const int w    = t >> 6;

    {
        const int n = t & 63;
        const int kb = (t >> 6) * 16;
#pragma unroll
        for (int i = 0; i < 16; ++i) {
            const int k = kb + i;
            W2t[n * 72 + k] = f2bf(W2[k * 64 + n]);
        }
    }
    {
        const int k = t >> 4;
        const int c = t & 15;
#pragma unroll
        for (int i = 0; i < 8; ++i) {
            const int gn = blockIdx.x * 8 + i;
            const int gj = (int)knn[gn * 16 + k];
            const float4  vv = ((const float4*)(out + (size_t)gn * CH))[c];
            const ushort4 uu = ((const ushort4*)(ubuf + (size_t)gj * CH))[c];
            ushort4 hv;
            hv.x = f2bf(fmaxf(vv.x + bf2f(uu.x), 0.f));
            hv.y = f2bf(fmaxf(vv.y + bf2f(uu.y), 0.f));
            hv.z = f2bf(fmaxf(vv.z + bf2f(uu.z), 0.f));
            hv.w = f2bf(fmaxf(vv.w + bf2f(uu.w), 0.f));
            const int r2 = i * 16 + k;
            *(ushort4*)(h + r2 * 72 + c * 4) = hv;
        }
    }
    __syncthreads();

    const int m16 = lane & 15;
    const int q   = lane >> 4;

    floatx4 acc[2][4];
#pragma unroll
    for (int i = 0; i < 2; ++i)
#pragma unroll
        for (int nt = 0; nt < 4; ++nt) acc[i][nt] = (floatx4){0.f, 0.f, 0.f, 0.f};

#pragma unroll
    for (int kk = 0; kk < 64; kk += 32) {
        const short8 a0 = *(const short8*)(h + ((w * 2 + 0) * 16 + m16) * 72 + kk + q * 8);
        const short8 a1 = *(const short8*)(h + ((w * 2 + 1) * 16 + m16) * 72 + kk + q * 8);
#pragma unroll
        for (int nt = 0; nt < 4; ++nt) {
            const short8 b = *(const short8*)(W2t + (nt * 16 + m16) * 72 + kk + q * 8);
            acc[0][nt] = __builtin_amdgcn_mfma_f32_16x16x32_bf16(a0, b, acc[0][nt], 0, 0, 0);
            acc[1][nt] = __builtin_amdgcn_mfma_f32_16x16x32_bf16(a1, b, acc[1][nt], 0, 0, 0);
        }
    }

#pragma unroll
    for (int i = 0; i < 2; ++i) {
        const int mt = w * 2 + i;
        const int gn = blockIdx.x * 8 + mt;
#pragma unroll
        for (int nt = 0; nt < 4; ++nt) {
            float m0 = fmaxf(fmaxf(acc[i][nt][0], acc[i][nt][1]),
                             fmaxf(acc[i][nt][2], acc[i][nt][3]));
            m0 = fmaxf(m0, __shfl_xor(m0, 16));
            m0 = fmaxf(m0, __shfl_xor(m0, 32));
            if (lane < 16)
                out[(size_t)gn * CH + nt * 16 + lane] = m0 + b2[nt * 16 + lane];
        }
    }
}

extern "C" void kernel_launch(void* const* d_in, const int* in_sizes, int n_in,
                              void* d_out, int out_size, void* d_ws, size_t ws_size,
                              hipStream_t stream) {
    const float* x   = (const float*)d_in[0];
    const float* pos = (const float*)d_in[1];
    const float* W1  = (const float*)d_in[2];
    const float* b1  = (const float*)d_in[3];
    const float* W2  = (const float*)d_in[4];
    const float* b2  = (const float*)d_in[5];
    float* out = (float*)d_out;

    char* ws = (char*)d_ws;
    unsigned short* knn  = (unsigned short*)ws;                    // 512 KB @ 0
    unsigned short* ubuf = (unsigned short*)(ws + 524288);         // 2 MB
    int*    counts = (int*)(ws + 2621440);                         // 128 KB
    int*    starts = (int*)(ws + 2752512);                         // 128 KB + sentinel
    int*    cursor = (int*)(ws + 2883600);                         // 128 KB
    float4* spos   = (float4*)(ws + 3014672);                      // 256 KB
    unsigned short* sidx = (unsigned short*)(ws + 3276816);        // 32 KB

    hipMemsetAsync(counts, 0, GCELLS * sizeof(int), stream);
    count_prep_kernel<<<320, 256, 0, stream>>>(pos, counts, x, W1, b1, out, ubuf);
    scan_kernel<<<1, 1024, 0, stream>>>(counts, starts, cursor);
    grid_scatter_kernel<<<NPTS / 256, 256, 0, stream>>>(pos, cursor, spos, sidx);
    knn_grid_kernel<<<NPTS / 16, 256, 0, stream>>>(pos, spos, sidx, starts, knn);
    edge_kernel<<<NPTS / 8, 256, 0, stream>>>(ubuf, W2, b2, knn, out);
}